// Round 11
// baseline (215.480 us; speedup 1.0000x reference)
//
#include <hip/hip_runtime.h>
#include <math.h>

typedef unsigned short u16;
typedef unsigned int u32;
typedef __attribute__((ext_vector_type(8))) short short8;
typedef __attribute__((ext_vector_type(4))) float f32x4;
typedef __attribute__((ext_vector_type(4))) u16 u16x4;

__device__ __forceinline__ void gload16(const void* g, void* l) {
    __builtin_amdgcn_global_load_lds(
        (__attribute__((address_space(1))) u32*)g,
        (__attribute__((address_space(3))) u32*)l, 16, 0, 0);
}

__device__ __forceinline__ u16 f2bf_rne(float v) {
    u32 u = __builtin_bit_cast(u32, v);
    return (u16)((u + 0x7FFFu + ((u >> 16) & 1u)) >> 16);
}
__device__ __forceinline__ float bf2f(u16 h) {
    u32 u = ((u32)h) << 16;
    return __builtin_bit_cast(float, u);
}
__device__ __forceinline__ void splt(float v, u16& h, u16& l) {
    h = f2bf_rne(v);
    l = f2bf_rne(v - bf2f(h));
}

enum { EP_RELU, EP_MUL };            // mlp_pf epilogues
enum { EP_PART };                    // gemm_pf epilogue

// Single-barrier K-step (T3-minimal): STAGE(t+1) issued early; ds_read+MFMA on t;
// vmcnt(0) (drains t+1's loads, issued a full compute-phase ago -> cheap);
// ONE barrier (all waves' ds_reads of buf t done -> overwritable; LDS of t+1 visible).

// ================= merged MLP GEMM =================
// A [12288,512] hi/lo; sections of 4096 rows: 0=KEY,1=QUERY (shared W), 2=VALUE
// grid MUST be (8,96,1). XCD-chunked remap: panel = xcd*12 + slot (12 A-panels/XCD).
template<int EP>
__global__ __launch_bounds__(256)
void mlp_pf(const u16* __restrict__ Ah, const u16* __restrict__ Al,
            const u16* __restrict__ BHkq, const u16* __restrict__ BLkq,
            const u16* __restrict__ BHv, const u16* __restrict__ BLv,
            const float* __restrict__ bias_kq, const float* __restrict__ bias_v,
            const float* __restrict__ Xk, const float* __restrict__ Xq,
            const float* __restrict__ Xv,
            u16* __restrict__ Ch, u16* __restrict__ Cl)
{
    __shared__ u16 LAh[2][128 * 32];
    __shared__ u16 LAl[2][128 * 32];
    __shared__ u16 LBh[2][64 * 32];
    __shared__ u16 LBl[2][64 * 32];

    const int tid = threadIdx.x;
    const int lane = tid & 63;
    const int wave = tid >> 6;
    const int wr = wave >> 1, wc = wave & 1;
    const int fr = lane & 15, kg = lane >> 4;

    const int L = blockIdx.y * 8 + blockIdx.x;
    const int xcd = L & 7;
    const int i = L >> 3;                 // 0..95
    const int panel = xcd * 12 + (i >> 3);
    const int m0 = panel * 128, n0 = (i & 7) * 64;
    const int sec = panel >> 5;

    const u16* Bh = (sec == 2) ? BHv : BHkq;
    const u16* Bl = (sec == 2) ? BLv : BLkq;
    const float* bias = (sec == 2) ? bias_v : bias_kq;

    f32x4 acc[4][2];
    #pragma unroll
    for (int a = 0; a < 4; ++a)
        #pragma unroll
        for (int j = 0; j < 2; ++j)
            acc[a][j] = (f32x4){0.f, 0.f, 0.f, 0.f};

    auto STAGE = [&](int buf, int kk) {
        #pragma unroll
        for (int h = 0; h < 2; ++h) {
            int c = h * 256 + tid;
            long so = (long)(m0 + (c >> 2)) * 512 + kk + (c & 3) * 8;
            gload16(Ah + so, &LAh[buf][c * 8]);
        }
        #pragma unroll
        for (int h = 0; h < 2; ++h) {
            int c = h * 256 + tid;
            long so = (long)(m0 + (c >> 2)) * 512 + kk + (c & 3) * 8;
            gload16(Al + so, &LAl[buf][c * 8]);
        }
        {
            int c = tid;
            long so = (long)(n0 + (c >> 2)) * 512 + kk + (c & 3) * 8;
            gload16(Bh + so, &LBh[buf][c * 8]);
            gload16(Bl + so, &LBl[buf][c * 8]);
        }
    };

    auto COMPUTE = [&](int buf) {
        short8 ah[4], al[4], bh[2], bl[2];
        #pragma unroll
        for (int a = 0; a < 4; ++a) {
            int off = (wr * 64 + a * 16 + fr) * 32 + kg * 8;
            ah[a] = *(const short8*)&LAh[buf][off];
            al[a] = *(const short8*)&LAl[buf][off];
        }
        #pragma unroll
        for (int j = 0; j < 2; ++j) {
            int off = (wc * 32 + j * 16 + fr) * 32 + kg * 8;
            bh[j] = *(const short8*)&LBh[buf][off];
            bl[j] = *(const short8*)&LBl[buf][off];
        }
        #pragma unroll
        for (int a = 0; a < 4; ++a)
            #pragma unroll
            for (int j = 0; j < 2; ++j) {
                acc[a][j] = __builtin_amdgcn_mfma_f32_16x16x32_bf16(ah[a], bh[j], acc[a][j], 0, 0, 0);
                acc[a][j] = __builtin_amdgcn_mfma_f32_16x16x32_bf16(ah[a], bl[j], acc[a][j], 0, 0, 0);
                acc[a][j] = __builtin_amdgcn_mfma_f32_16x16x32_bf16(al[a], bh[j], acc[a][j], 0, 0, 0);
            }
    };

    STAGE(0, 0);
    asm volatile("s_waitcnt vmcnt(0)" ::: "memory");
    __builtin_amdgcn_s_barrier();
    int cur = 0;
    for (int t = 0; t < 15; ++t) {
        STAGE(cur ^ 1, (t + 1) << 5);
        COMPUTE(cur);
        asm volatile("s_waitcnt vmcnt(0)" ::: "memory");
        __builtin_amdgcn_s_barrier();
        cur ^= 1;
    }
    COMPUTE(cur);

    const float* X = (EP == EP_MUL) ? ((sec == 0) ? Xk : (sec == 1) ? Xq : Xv) : nullptr;

    #pragma unroll
    for (int a = 0; a < 4; ++a)
        #pragma unroll
        for (int j = 0; j < 2; ++j)
            #pragma unroll
            for (int r = 0; r < 4; ++r) {
                int row = m0 + wr * 64 + a * 16 + kg * 4 + r;
                int col = n0 + wc * 32 + j * 16 + fr;
                float v = acc[a][j][r] + bias[col];
                if constexpr (EP == EP_RELU) {
                    v = fmaxf(v, 0.f);
                } else {
                    v *= X[(long)(row - (sec << 12)) * 512 + col];
                }
                long o = (long)row * 512 + col;
                u16 h, l; splt(v, h, l);
                Ch[o] = h; Cl[o] = l;
            }
}

// ================= 128x128 dist GEMM: sT[b,q,key] = -(qs.ks/sqrt512)^2/2 =================
// grid MUST be (16,16,2) = 512 blocks (2/CU uniform). XCD owns one (batch, 8x8 quadrant).
__global__ __launch_bounds__(256)
void dist2(const u16* __restrict__ QH, const u16* __restrict__ QL,
           const u16* __restrict__ KH, const u16* __restrict__ KL,
           u16* __restrict__ S)
{
    __shared__ u16 LAh[2][128 * 32];
    __shared__ u16 LAl[2][128 * 32];
    __shared__ u16 LBh[2][128 * 32];
    __shared__ u16 LBl[2][128 * 32];

    const int tid = threadIdx.x;
    const int lane = tid & 63;
    const int wave = tid >> 6;
    const int wr = wave >> 1, wc = wave & 1;
    const int fr = lane & 15, kg = lane >> 4;

    const int L = (blockIdx.z * 16 + blockIdx.y) * 16 + blockIdx.x;
    const int xcd = L & 7;
    const int pos = L >> 3;                 // 0..63
    const int b = xcd >> 2, quad = xcd & 3;
    const int mi = (quad >> 1) * 8 + (pos >> 3);
    const int ni = (quad & 1) * 8 + (pos & 7);
    const int m0 = mi * 128, n0 = ni * 128;

    const u16* Ah = QH + (long)b * 1048576;
    const u16* Al = QL + (long)b * 1048576;
    const u16* Bh = KH + (long)b * 1048576;
    const u16* Bl = KL + (long)b * 1048576;

    f32x4 acc[4][4];
    #pragma unroll
    for (int a = 0; a < 4; ++a)
        #pragma unroll
        for (int j = 0; j < 4; ++j)
            acc[a][j] = (f32x4){0.f, 0.f, 0.f, 0.f};

    auto STAGE = [&](int buf, int kk) {
        #pragma unroll
        for (int h = 0; h < 2; ++h) {
            int c = h * 256 + tid;
            long so = (long)(m0 + (c >> 2)) * 512 + kk + (c & 3) * 8;
            gload16(Ah + so, &LAh[buf][c * 8]);
        }
        #pragma unroll
        for (int h = 0; h < 2; ++h) {
            int c = h * 256 + tid;
            long so = (long)(m0 + (c >> 2)) * 512 + kk + (c & 3) * 8;
            gload16(Al + so, &LAl[buf][c * 8]);
        }
        #pragma unroll
        for (int h = 0; h < 2; ++h) {
            int c = h * 256 + tid;
            long so = (long)(n0 + (c >> 2)) * 512 + kk + (c & 3) * 8;
            gload16(Bh + so, &LBh[buf][c * 8]);
        }
        #pragma unroll
        for (int h = 0; h < 2; ++h) {
            int c = h * 256 + tid;
            long so = (long)(n0 + (c >> 2)) * 512 + kk + (c & 3) * 8;
            gload16(Bl + so, &LBl[buf][c * 8]);
        }
    };

    auto COMPUTE = [&](int buf) {
        short8 ah[4], al[4], bh[4], bl[4];
        #pragma unroll
        for (int a = 0; a < 4; ++a) {
            int off = (wr * 64 + a * 16 + fr) * 32 + kg * 8;
            ah[a] = *(const short8*)&LAh[buf][off];
            al[a] = *(const short8*)&LAl[buf][off];
        }
        #pragma unroll
        for (int j = 0; j < 4; ++j) {
            int off = (wc * 64 + j * 16 + fr) * 32 + kg * 8;
            bh[j] = *(const short8*)&LBh[buf][off];
            bl[j] = *(const short8*)&LBl[buf][off];
        }
        #pragma unroll
        for (int a = 0; a < 4; ++a)
            #pragma unroll
            for (int j = 0; j < 4; ++j) {
                acc[a][j] = __builtin_amdgcn_mfma_f32_16x16x32_bf16(ah[a], bh[j], acc[a][j], 0, 0, 0);
                acc[a][j] = __builtin_amdgcn_mfma_f32_16x16x32_bf16(ah[a], bl[j], acc[a][j], 0, 0, 0);
                acc[a][j] = __builtin_amdgcn_mfma_f32_16x16x32_bf16(al[a], bh[j], acc[a][j], 0, 0, 0);
            }
    };

    STAGE(0, 0);
    asm volatile("s_waitcnt vmcnt(0)" ::: "memory");
    __builtin_amdgcn_s_barrier();
    int cur = 0;
    for (int t = 0; t < 15; ++t) {
        STAGE(cur ^ 1, (t + 1) << 5);
        COMPUTE(cur);
        asm volatile("s_waitcnt vmcnt(0)" ::: "memory");
        __builtin_amdgcn_s_barrier();
        cur ^= 1;
    }
    COMPUTE(cur);

    u16* Sb = S + (long)b * 8388608;
    #pragma unroll
    for (int a = 0; a < 4; ++a)
        #pragma unroll
        for (int j = 0; j < 4; ++j)
            #pragma unroll
            for (int r = 0; r < 4; ++r) {
                int row = m0 + wr * 64 + a * 16 + kg * 4 + r;
                int col = n0 + wc * 64 + j * 16 + fr;
                float v = acc[a][j][r];
                v = -(v * v) * (1.0f / 1024.0f);
                u16 h, l; splt(v, h, l);
                u16* p = Sb + (long)row * 4096 + col;
                p[0] = h; p[2048] = l;
            }
}

// ================= 128x128 split-K GEMM (context) =================
// grid (4,16,8): gz = b*4 + s; contiguous-panel XCD remap; partials f32.
// s<3 -> Cf0[(b*3+s)<<20]; s==3 -> Cf3[b<<20].
__global__ __launch_bounds__(256)
void gemm2(const u16* __restrict__ Ah, const u16* __restrict__ Al, int lda, long sA,
           const u16* __restrict__ Bh, const u16* __restrict__ Bl, int ldb, long sB,
           float* __restrict__ Cf0, float* __restrict__ Cf3)
{
    __shared__ u16 LAh[2][128 * 32];
    __shared__ u16 LAl[2][128 * 32];
    __shared__ u16 LBh[2][128 * 32];
    __shared__ u16 LBl[2][128 * 32];

    const int tid = threadIdx.x;
    const int lane = tid & 63;
    const int wave = tid >> 6;
    const int wr = wave >> 1, wc = wave & 1;
    const int fr = lane & 15, kg = lane >> 4;

    // contiguous panel pinning: P = 16*8 = 128 panels, 16 per XCD
    const int L = (blockIdx.z * 16 + blockIdx.y) * 4 + blockIdx.x;
    const int xcd = L & 7;
    const int i = L >> 3;                 // 0..63
    const int bx = i & 3;
    const int panel = xcd * 16 + (i >> 2);
    const int by = panel & 15;
    const int bz = panel >> 4;            // 0..7
    const int b = bz >> 2, s = bz & 3;
    const int k0 = s << 9;                // KS = 512

    Ah += b * sA; Al += b * sA;
    Bh += b * sB; Bl += b * sB;
    float* Cf = (s < 3) ? (Cf0 + ((long)(b * 3 + s) << 20))
                        : (Cf3 + ((long)b << 20));

    const int m0 = by * 128, n0 = bx * 128;

    f32x4 acc[4][4];
    #pragma unroll
    for (int a = 0; a < 4; ++a)
        #pragma unroll
        for (int j = 0; j < 4; ++j)
            acc[a][j] = (f32x4){0.f, 0.f, 0.f, 0.f};

    auto STAGE = [&](int buf, int kk) {
        #pragma unroll
        for (int h = 0; h < 2; ++h) {
            int c = h * 256 + tid;
            long so = (long)(m0 + (c >> 2)) * lda + kk + (c & 3) * 8;
            gload16(Ah + so, &LAh[buf][c * 8]);
        }
        #pragma unroll
        for (int h = 0; h < 2; ++h) {
            int c = h * 256 + tid;
            long so = (long)(m0 + (c >> 2)) * lda + kk + (c & 3) * 8;
            gload16(Al + so, &LAl[buf][c * 8]);
        }
        #pragma unroll
        for (int h = 0; h < 2; ++h) {
            int c = h * 256 + tid;
            long so = (long)(n0 + (c >> 2)) * ldb + kk + (c & 3) * 8;
            gload16(Bh + so, &LBh[buf][c * 8]);
        }
        #pragma unroll
        for (int h = 0; h < 2; ++h) {
            int c = h * 256 + tid;
            long so = (long)(n0 + (c >> 2)) * ldb + kk + (c & 3) * 8;
            gload16(Bl + so, &LBl[buf][c * 8]);
        }
    };

    auto COMPUTE = [&](int buf) {
        short8 ah[4], al[4], bh[4], bl[4];
        #pragma unroll
        for (int a = 0; a < 4; ++a) {
            int off = (wr * 64 + a * 16 + fr) * 32 + kg * 8;
            ah[a] = *(const short8*)&LAh[buf][off];
            al[a] = *(const short8*)&LAl[buf][off];
        }
        #pragma unroll
        for (int j = 0; j < 4; ++j) {
            int off = (wc * 64 + j * 16 + fr) * 32 + kg * 8;
            bh[j] = *(const short8*)&LBh[buf][off];
            bl[j] = *(const short8*)&LBl[buf][off];
        }
        #pragma unroll
        for (int a = 0; a < 4; ++a)
            #pragma unroll
            for (int j = 0; j < 4; ++j) {
                acc[a][j] = __builtin_amdgcn_mfma_f32_16x16x32_bf16(ah[a], bh[j], acc[a][j], 0, 0, 0);
                acc[a][j] = __builtin_amdgcn_mfma_f32_16x16x32_bf16(ah[a], bl[j], acc[a][j], 0, 0, 0);
                acc[a][j] = __builtin_amdgcn_mfma_f32_16x16x32_bf16(al[a], bh[j], acc[a][j], 0, 0, 0);
            }
    };

    STAGE(0, k0);
    asm volatile("s_waitcnt vmcnt(0)" ::: "memory");
    __builtin_amdgcn_s_barrier();
    int cur = 0;
    for (int t = 0; t < 15; ++t) {
        STAGE(cur ^ 1, k0 + ((t + 1) << 5));
        COMPUTE(cur);
        asm volatile("s_waitcnt vmcnt(0)" ::: "memory");
        __builtin_amdgcn_s_barrier();
        cur ^= 1;
    }
    COMPUTE(cur);

    #pragma unroll
    for (int a = 0; a < 4; ++a)
        #pragma unroll
        for (int j = 0; j < 4; ++j)
            #pragma unroll
            for (int r = 0; r < 4; ++r) {
                int row = m0 + wr * 64 + a * 16 + kg * 4 + r;
                int col = n0 + wc * 64 + j * 16 + fr;
                Cf[(long)row * 512 + col] = acc[a][j][r];
            }
}

// ================= generic 128x64 split GEMM with XCD remap (outproj) =================
template<int EP>
__global__ __launch_bounds__(256)
void gemm_pf(int K, int nsl, int KS,
             const u16* __restrict__ Ah, const u16* __restrict__ Al, int lda, long sA,
             const u16* __restrict__ Bh, const u16* __restrict__ Bl, int ldb, long sB,
             float* __restrict__ Cf, int ldc, long sC)
{
    __shared__ u16 LAh[2][128 * 32];
    __shared__ u16 LAl[2][128 * 32];
    __shared__ u16 LBh[2][64 * 32];
    __shared__ u16 LBl[2][64 * 32];

    const int tid = threadIdx.x;
    const int lane = tid & 63;
    const int wave = tid >> 6;
    const int wr = wave >> 1, wc = wave & 1;
    const int fr = lane & 15, kg = lane >> 4;

    int bx, by, bz;
    {
        const int gx = gridDim.x, gy = gridDim.y;
        const int L = (blockIdx.z * gy + blockIdx.y) * gx + blockIdx.x;
        const int xcd = L & 7;
        const int i = L >> 3;
        const int P = gy * gridDim.z;
        const int ppx = P >> 3;
        bx = i % gx;
        const int panel = xcd * ppx + i / gx;
        by = panel % gy;
        bz = panel / gy;
    }

    const int b = bz / nsl;
    const int s = bz - b * nsl;
    const int k0 = s * KS;
    int k1 = k0 + KS; if (k1 > K) k1 = K;
    const int nt = (k1 - k0) >> 5;

    Ah += b * sA; Al += b * sA;
    Bh += b * sB; Bl += b * sB;
    const long cb = (long)bz * sC;

    const int m0 = by * 128, n0 = bx * 64;

    f32x4 acc[4][2];
    #pragma unroll
    for (int a = 0; a < 4; ++a)
        #pragma unroll
        for (int j = 0; j < 2; ++j)
            acc[a][j] = (f32x4){0.f, 0.f, 0.f, 0.f};

    auto STAGE = [&](int buf, int kk) {
        #pragma unroll
        for (int h = 0; h < 2; ++h) {
            int c = h * 256 + tid;
            long so = (long)(m0 + (c >> 2)) * lda + kk + (c & 3) * 8;
            gload16(Ah + so, &LAh[buf][c * 8]);
        }
        #pragma unroll
        for (int h = 0; h < 2; ++h) {
            int c = h * 256 + tid;
            long so = (long)(m0 + (c >> 2)) * lda + kk + (c & 3) * 8;
            gload16(Al + so, &LAl[buf][c * 8]);
        }
        {
            int c = tid;
            long so = (long)(n0 + (c >> 2)) * ldb + kk + (c & 3) * 8;
            gload16(Bh + so, &LBh[buf][c * 8]);
            gload16(Bl + so, &LBl[buf][c * 8]);
        }
    };

    auto COMPUTE = [&](int buf) {
        short8 ah[4], al[4], bh[2], bl[2];
        #pragma unroll
        for (int a = 0; a < 4; ++a) {
            int off = (wr * 64 + a * 16 + fr) * 32 + kg * 8;
            ah[a] = *(const short8*)&LAh[buf][off];
            al[a] = *(const short8*)&LAl[buf][off];
        }
        #pragma unroll
        for (int j = 0; j < 2; ++j) {
            int off = (wc * 32 + j * 16 + fr) * 32 + kg * 8;
            bh[j] = *(const short8*)&LBh[buf][off];
            bl[j] = *(const short8*)&LBl[buf][off];
        }
        #pragma unroll
        for (int a = 0; a < 4; ++a)
            #pragma unroll
            for (int j = 0; j < 2; ++j) {
                acc[a][j] = __builtin_amdgcn_mfma_f32_16x16x32_bf16(ah[a], bh[j], acc[a][j], 0, 0, 0);
                acc[a][j] = __builtin_amdgcn_mfma_f32_16x16x32_bf16(ah[a], bl[j], acc[a][j], 0, 0, 0);
                acc[a][j] = __builtin_amdgcn_mfma_f32_16x16x32_bf16(al[a], bh[j], acc[a][j], 0, 0, 0);
            }
    };

    STAGE(0, k0);
    asm volatile("s_waitcnt vmcnt(0)" ::: "memory");
    __builtin_amdgcn_s_barrier();
    int cur = 0;
    for (int t = 0; t < nt - 1; ++t) {
        STAGE(cur ^ 1, k0 + ((t + 1) << 5));
        COMPUTE(cur);
        asm volatile("s_waitcnt vmcnt(0)" ::: "memory");
        __builtin_amdgcn_s_barrier();
        cur ^= 1;
    }
    COMPUTE(cur);

    #pragma unroll
    for (int a = 0; a < 4; ++a)
        #pragma unroll
        for (int j = 0; j < 2; ++j)
            #pragma unroll
            for (int r = 0; r < 4; ++r) {
                int row = m0 + wr * 64 + a * 16 + kg * 4 + r;
                int col = n0 + wc * 32 + j * 16 + fr;
                Cf[cb + (long)row * ldc + col] = acc[a][j][r];
            }
}

// softmax over 2048 keys; in/out = hi/lo bf16 pairs, row stride 4096 u16
__global__ __launch_bounds__(256)
void softmax16(u16* __restrict__ S)
{
    long row = blockIdx.x;
    u16* hi = S + row * 4096;
    u16* lo = hi + 2048;
    int tid = threadIdx.x;
    int lane = tid & 63, w = tid >> 6;

    u16x4 h0 = ((u16x4*)hi)[tid * 2];
    u16x4 h1 = ((u16x4*)hi)[tid * 2 + 1];
    u16x4 l0 = ((u16x4*)lo)[tid * 2];
    u16x4 l1 = ((u16x4*)lo)[tid * 2 + 1];

    float v[8];
    #pragma unroll
    for (int i = 0; i < 4; ++i) {
        v[i]     = bf2f(h0[i]) + bf2f(l0[i]);
        v[4 + i] = bf2f(h1[i]) + bf2f(l1[i]);
    }

    float m = v[0];
    #pragma unroll
    for (int i = 1; i < 8; ++i) m = fmaxf(m, v[i]);
    #pragma unroll
    for (int o = 32; o; o >>= 1) m = fmaxf(m, __shfl_xor(m, o));

    __shared__ float redm[4];
    __shared__ float reds[4];
    if (lane == 0) redm[w] = m;
    __syncthreads();
    m = fmaxf(fmaxf(redm[0], redm[1]), fmaxf(redm[2], redm[3]));

    float s = 0.f;
    #pragma unroll
    for (int i = 0; i < 8; ++i) { v[i] = expf(v[i] - m); s += v[i]; }
    #pragma unroll
    for (int o = 32; o; o >>= 1) s += __shfl_xor(s, o);
    if (lane == 0) reds[w] = s;
    __syncthreads();
    s = reds[0] + reds[1] + reds[2] + reds[3];
    float inv = 1.0f / s;

    u16 h, l;
    #pragma unroll
    for (int i = 0; i < 4; ++i) {
        splt(v[i] * inv, h, l);     h0[i] = h; l0[i] = l;
        splt(v[4 + i] * inv, h, l); h1[i] = h; l1[i] = l;
    }
    ((u16x4*)hi)[tid * 2] = h0;
    ((u16x4*)hi)[tid * 2 + 1] = h1;
    ((u16x4*)lo)[tid * 2] = l0;
    ((u16x4*)lo)[tid * 2 + 1] = l1;
}

// vs hi/lo [4096,512] (2 batches of 2048) -> vsT hi/lo [2][512][2048]
__global__ __launch_bounds__(256)
void transpose16(const u16* __restrict__ vH, const u16* __restrict__ vL,
                 u16* __restrict__ tH, u16* __restrict__ tL)
{
    __shared__ float t[32][33];
    int b = blockIdx.z;
    int c0 = blockIdx.x * 32;
    int r0 = blockIdx.y * 32;
    int tx = threadIdx.x, ty = threadIdx.y;
    #pragma unroll
    for (int k = 0; k < 4; ++k) {
        long idx = (long)(b * 2048 + r0 + ty + 8 * k) * 512 + c0 + tx;
        t[ty + 8 * k][tx] = bf2f(vH[idx]) + bf2f(vL[idx]);
    }
    __syncthreads();
    long ob = (long)b * 512 * 2048;
    #pragma unroll
    for (int k = 0; k < 4; ++k) {
        float v = t[tx][ty + 8 * k];
        u16 h, l; splt(v, h, l);
        long o = ob + (long)(c0 + ty + 8 * k) * 2048 + r0 + tx;
        tH[o] = h; tL[o] = l;
    }
}

// split 7 weights in one launch; dst layout: [wi][hi 262144 | lo 262144]
__global__ __launch_bounds__(256)
void split_w(const float* __restrict__ w0, const float* __restrict__ w1,
             const float* __restrict__ w2, const float* __restrict__ w3,
             const float* __restrict__ w4, const float* __restrict__ w5,
             const float* __restrict__ w6, u16* __restrict__ dst)
{
    int wi = blockIdx.y;
    const float* src;
    switch (wi) {
        case 0: src = w0; break; case 1: src = w1; break;
        case 2: src = w2; break; case 3: src = w3; break;
        case 4: src = w4; break; case 5: src = w5; break;
        default: src = w6; break;
    }
    u16* hi = dst + (long)wi * 524288;
    u16* lo = hi + 262144;
    int i = blockIdx.x * 256 + threadIdx.x;
    float4 v = ((const float4*)src)[i];
    u16x4 h4, l4; u16 h, l;
    splt(v.x, h, l); h4.x = h; l4.x = l;
    splt(v.y, h, l); h4.y = h; l4.y = l;
    splt(v.z, h, l); h4.z = h; l4.z = l;
    splt(v.w, h, l); h4.w = h; l4.w = l;
    ((u16x4*)hi)[i] = h4;
    ((u16x4*)lo)[i] = l4;
}

// split 3 inputs (KEY,QUERY,VALUE) into stacked [12288,512] hi/lo
__global__ __launch_bounds__(256)
void split_in(const float* __restrict__ k, const float* __restrict__ q,
              const float* __restrict__ vv, u16* __restrict__ hi, u16* __restrict__ lo)
{
    int sec = blockIdx.y;
    const float* src = (sec == 0) ? k : (sec == 1) ? q : vv;
    long base4 = (long)sec * 524288;
    int i = blockIdx.x * 256 + threadIdx.x;
    float4 v = ((const float4*)src)[i];
    u16x4 h4, l4; u16 h, l;
    splt(v.x, h, l); h4.x = h; l4.x = l;
    splt(v.y, h, l); h4.y = h; l4.y = l;
    splt(v.z, h, l); h4.z = h; l4.z = l;
    splt(v.w, h, l); h4.w = h; l4.w = l;
    ((u16x4*)(hi))[base4 + i] = h4;
    ((u16x4*)(lo))[base4 + i] = l4;
}

// ct = split(sum of 4 ctx partials); P012 layout [b*3+s][2^20], P3 layout [b][2^20]
__global__ __launch_bounds__(256)
void reduce_ctx4(const float* __restrict__ P012, const float* __restrict__ P3,
                 u16* __restrict__ ctH, u16* __restrict__ ctL)
{
    int i4 = blockIdx.x * 256 + threadIdx.x;     // 524288 float4s
    long e = (long)i4 * 4;
    int b = (int)(e >> 20);
    long r = e & ((1L << 20) - 1);
    const float* base = P012 + ((long)(b * 3) << 20) + r;
    float4 v0 = *(const float4*)base;
    float4 v1 = *(const float4*)(base + (1L << 20));
    float4 v2 = *(const float4*)(base + (2L << 20));
    float4 v3 = *(const float4*)(P3 + ((long)b << 20) + r);
    u16x4 h4, l4; u16 h, l;
    splt(v0.x + v1.x + v2.x + v3.x, h, l); h4.x = h; l4.x = l;
    splt(v0.y + v1.y + v2.y + v3.y, h, l); h4.y = h; l4.y = l;
    splt(v0.z + v1.z + v2.z + v3.z, h, l); h4.z = h; l4.z = l;
    splt(v0.w + v1.w + v2.w + v3.w, h, l); h4.w = h; l4.w = l;
    ((u16x4*)ctH)[i4] = h4;
    ((u16x4*)ctL)[i4] = l4;
}

// out = P0 + P1 + bias
__global__ __launch_bounds__(256)
void reduce_out(const float* __restrict__ P, const float* __restrict__ bias,
                float* __restrict__ out)
{
    int i4 = blockIdx.x * 256 + threadIdx.x;     // 524288 float4s
    long e = (long)i4 * 4;
    float4 a = ((const float4*)P)[i4];
    float4 c = ((const float4*)(P + 2097152))[i4];
    float4 bb = *(const float4*)(bias + (e & 511));
    float4 o;
    o.x = a.x + c.x + bb.x;
    o.y = a.y + c.y + bb.y;
    o.z = a.z + c.z + bb.z;
    o.w = a.w + c.w + bb.w;
    ((float4*)out)[i4] = o;
}

extern "C" void kernel_launch(void* const* d_in, const int* in_sizes, int n_in,
                              void* d_out, int out_size, void* d_ws, size_t ws_size,
                              hipStream_t stream)
{
    const float* KEY   = (const float*)d_in[0];
    const float* VALUE = (const float*)d_in[1];
    const float* QUERY = (const float*)d_in[2];
    const float* W1w = (const float*)d_in[3];
    const float* W1b = (const float*)d_in[4];
    const float* W2w = (const float*)d_in[5];
    const float* W2b = (const float*)d_in[6];
    const float* W3w = (const float*)d_in[7];
    const float* W3b = (const float*)d_in[8];
    const float* V1w = (const float*)d_in[9];
    const float* V1b = (const float*)d_in[10];
    const float* V2w = (const float*)d_in[11];
    const float* V2b = (const float*)d_in[12];
    const float* V3w = (const float*)d_in[13];
    const float* V3b = (const float*)d_in[14];
    const float* Wow = (const float*)d_in[15];
    const float* Wob = (const float*)d_in[16];
    float* out = (float*)d_out;

    const long SEC  = 4096L * 512;     // 2,097,152 u16 per section
    const long FULL = 3 * SEC;         // 6,291,456

    // ---- workspace layout (82,837,504 B total, identical to proven R10) ----
    u16* Wb = (u16*)d_ws;                        // 7 x (hi|lo) = 3,670,016 u16
    u16* cH = Wb + 3670016;                      // [12288,512] hi
    u16* cL = cH + FULL;                         // lo
    u16* R1 = cL + FULL;                         // 4*FULL u16 region
    u16* h1H = R1,            *h1L = R1 + FULL;
    u16* h2H = R1 + 2 * FULL, *h2L = R1 + 3 * FULL;
    // post-L3 aliases inside R1 (h1,h2 dead):
    u16* sTu = R1;                               // scores [2][2048][4096] u16 (33.5 MB)
    u16* vtH = R1 + 16777216;                    // vsT hi [2][512][2048]
    u16* vtL = vtH + 2097152;
    // ctx partials: slices s<3 in c region (24 MB), s==3 in R1 tail (8 MB)
    float* Pctx012 = (float*)cH;                 // [2*3][2^20] f32
    float* Pctx3   = (float*)(R1 + 20971520);    // [2][2^20] f32
    // after ctx: sTu dead -> ct + Pout live there
    u16* ctH = R1;                               // ctx hi [4096,512]
    u16* ctL = R1 + 2097152;
    float* Pout = (float*)(R1 + 4194304);        // [2][2^21] f32 = 16 MB

    u16* wH6 = Wb + 6L * 524288;
    u16* wL6 = wH6 + 262144;

    dim3 blk(256);

    split_w<<<dim3(256, 7), blk, 0, stream>>>(W1w, W2w, W3w, V1w, V2w, V3w, Wow, Wb);
    split_in<<<dim3(2048, 3), blk, 0, stream>>>(KEY, QUERY, VALUE, cH, cL);

    // ---- merged MLP: 3 layers over 12288 rows (c -> h1 -> h2 -> c) ----
    dim3 gL(8, 96, 1);
    mlp_pf<EP_RELU><<<gL, blk, 0, stream>>>(
        cH, cL, Wb, Wb + 262144, Wb + 3 * 524288, Wb + 3 * 524288 + 262144,
        W1b, V1b, nullptr, nullptr, nullptr, h1H, h1L);
    mlp_pf<EP_RELU><<<gL, blk, 0, stream>>>(
        h1H, h1L, Wb + 524288, Wb + 524288 + 262144, Wb + 4 * 524288, Wb + 4 * 524288 + 262144,
        W2b, V2b, nullptr, nullptr, nullptr, h2H, h2L);
    mlp_pf<EP_MUL><<<gL, blk, 0, stream>>>(
        h2H, h2L, Wb + 2 * 524288, Wb + 2 * 524288 + 262144, Wb + 5 * 524288, Wb + 5 * 524288 + 262144,
        W3b, V3b, KEY, QUERY, VALUE, cH, cL);
    // c now holds: ks rows 0-4095, qs rows 4096-8191, vs rows 8192-12287

    // vs -> vsT hi/lo
    transpose16<<<dim3(16, 64, 2), dim3(32, 8), 0, stream>>>(
        cH + 2 * SEC, cL + 2 * SEC, vtH, vtL);

    // dist: sT[b,q,key] hi/lo — 128x128 tiles, 512 blocks = 2/CU uniform
    dist2<<<dim3(16, 16, 2), blk, 0, stream>>>(
        cH + SEC, cL + SEC,      // qs hi/lo
        cH, cL,                  // ks hi/lo
        sTu);

    // softmax over keys (hi/lo in place)
    softmax16<<<dim3(4096), blk, 0, stream>>>(sTu);

    // context: 128x128 tiles, split-K4, 512 blocks = 2/CU uniform
    gemm2<<<dim3(4, 16, 8), blk, 0, stream>>>(
        sTu, sTu + 2048, 4096, 8388608,
        vtH, vtL, 2048, 1048576,
        Pctx012, Pctx3);

    reduce_ctx4<<<dim3(2048), blk, 0, stream>>>(Pctx012, Pctx3, ctH, ctL);

    // output projection split-K2 (512 blocks = 2/CU)
    gemm_pf<EP_PART><<<dim3(8, 32, 2), blk, 0, stream>>>(
        512, 2, 256,
        ctH, ctL, 512, 0,
        wH6, wL6, 512, 0,
        Pout, 512, 2097152);

    reduce_out<<<dim3(2048), blk, 0, stream>>>(Pout, Wob, out);
}

// Round 12
// 201.251 us; speedup vs baseline: 1.0707x; 1.0707x over previous
//
#include <hip/hip_runtime.h>
#include <math.h>

typedef unsigned short u16;
typedef unsigned int u32;
typedef __attribute__((ext_vector_type(8))) short short8;
typedef __attribute__((ext_vector_type(4))) float f32x4;
typedef __attribute__((ext_vector_type(4))) u16 u16x4;

__device__ __forceinline__ void gload16(const void* g, void* l) {
    __builtin_amdgcn_global_load_lds(
        (__attribute__((address_space(1))) u32*)g,
        (__attribute__((address_space(3))) u32*)l, 16, 0, 0);
}

__device__ __forceinline__ u16 f2bf_rne(float v) {
    u32 u = __builtin_bit_cast(u32, v);
    return (u16)((u + 0x7FFFu + ((u >> 16) & 1u)) >> 16);
}
__device__ __forceinline__ float bf2f(u16 h) {
    u32 u = ((u32)h) << 16;
    return __builtin_bit_cast(float, u);
}
__device__ __forceinline__ void splt(float v, u16& h, u16& l) {
    h = f2bf_rne(v);
    l = f2bf_rne(v - bf2f(h));
}

enum { EP_RELU, EP_MUL };            // mlp_pf epilogues
enum { EP_PART };                    // gemm_pf epilogue

// ================= merged MLP GEMM with 2-phase counted-vmcnt prefetch =================
// A [12288,512] hi/lo; sections of 4096 rows: 0=KEY,1=QUERY (shared W), 2=VALUE
// grid MUST be (8,96,1). XCD-chunked remap: panel = xcd*12 + slot (12 A-panels/XCD).
template<int EP>
__global__ __launch_bounds__(256)
void mlp_pf(const u16* __restrict__ Ah, const u16* __restrict__ Al,
            const u16* __restrict__ BHkq, const u16* __restrict__ BLkq,
            const u16* __restrict__ BHv, const u16* __restrict__ BLv,
            const float* __restrict__ bias_kq, const float* __restrict__ bias_v,
            const float* __restrict__ Xk, const float* __restrict__ Xq,
            const float* __restrict__ Xv,
            u16* __restrict__ Ch, u16* __restrict__ Cl)
{
    __shared__ u16 LAh[2][128 * 32];
    __shared__ u16 LAl[2][128 * 32];
    __shared__ u16 LBh[2][64 * 32];
    __shared__ u16 LBl[2][64 * 32];

    const int tid = threadIdx.x;
    const int lane = tid & 63;
    const int wave = tid >> 6;
    const int wr = wave >> 1, wc = wave & 1;
    const int fr = lane & 15, kg = lane >> 4;

    const int L = blockIdx.y * 8 + blockIdx.x;
    const int xcd = L & 7;
    const int i = L >> 3;                 // 0..95
    const int panel = xcd * 12 + (i >> 3);
    const int m0 = panel * 128, n0 = (i & 7) * 64;
    const int sec = panel >> 5;

    const u16* Bh = (sec == 2) ? BHv : BHkq;
    const u16* Bl = (sec == 2) ? BLv : BLkq;
    const float* bias = (sec == 2) ? bias_v : bias_kq;

    f32x4 acc[4][2];
    #pragma unroll
    for (int a = 0; a < 4; ++a)
        #pragma unroll
        for (int j = 0; j < 2; ++j)
            acc[a][j] = (f32x4){0.f, 0.f, 0.f, 0.f};

    auto STAGE = [&](int buf, int kk) {
        #pragma unroll
        for (int h = 0; h < 2; ++h) {
            int c = h * 256 + tid;
            long so = (long)(m0 + (c >> 2)) * 512 + kk + (c & 3) * 8;
            gload16(Ah + so, &LAh[buf][c * 8]);
        }
        #pragma unroll
        for (int h = 0; h < 2; ++h) {
            int c = h * 256 + tid;
            long so = (long)(m0 + (c >> 2)) * 512 + kk + (c & 3) * 8;
            gload16(Al + so, &LAl[buf][c * 8]);
        }
        {
            int c = tid;
            long so = (long)(n0 + (c >> 2)) * 512 + kk + (c & 3) * 8;
            gload16(Bh + so, &LBh[buf][c * 8]);
            gload16(Bl + so, &LBl[buf][c * 8]);
        }
    };

    auto COMPUTE = [&](int buf) {
        short8 ah[4], al[4], bh[2], bl[2];
        #pragma unroll
        for (int a = 0; a < 4; ++a) {
            int off = (wr * 64 + a * 16 + fr) * 32 + kg * 8;
            ah[a] = *(const short8*)&LAh[buf][off];
            al[a] = *(const short8*)&LAl[buf][off];
        }
        #pragma unroll
        for (int j = 0; j < 2; ++j) {
            int off = (wc * 32 + j * 16 + fr) * 32 + kg * 8;
            bh[j] = *(const short8*)&LBh[buf][off];
            bl[j] = *(const short8*)&LBl[buf][off];
        }
        #pragma unroll
        for (int a = 0; a < 4; ++a)
            #pragma unroll
            for (int j = 0; j < 2; ++j) {
                acc[a][j] = __builtin_amdgcn_mfma_f32_16x16x32_bf16(ah[a], bh[j], acc[a][j], 0, 0, 0);
                acc[a][j] = __builtin_amdgcn_mfma_f32_16x16x32_bf16(ah[a], bl[j], acc[a][j], 0, 0, 0);
                acc[a][j] = __builtin_amdgcn_mfma_f32_16x16x32_bf16(al[a], bh[j], acc[a][j], 0, 0, 0);
            }
    };

    STAGE(0, 0);
    int cur = 0;
    for (int t = 0; t < 15; ++t) {
        STAGE(cur ^ 1, (t + 1) << 5);
        asm volatile("s_waitcnt vmcnt(6)" ::: "memory");
        __builtin_amdgcn_s_barrier();
        COMPUTE(cur);
        __builtin_amdgcn_s_barrier();
        cur ^= 1;
    }
    asm volatile("s_waitcnt vmcnt(0)" ::: "memory");
    __builtin_amdgcn_s_barrier();
    COMPUTE(cur);

    const float* X = (EP == EP_MUL) ? ((sec == 0) ? Xk : (sec == 1) ? Xq : Xv) : nullptr;

    #pragma unroll
    for (int a = 0; a < 4; ++a)
        #pragma unroll
        for (int j = 0; j < 2; ++j)
            #pragma unroll
            for (int r = 0; r < 4; ++r) {
                int row = m0 + wr * 64 + a * 16 + kg * 4 + r;
                int col = n0 + wc * 32 + j * 16 + fr;
                float v = acc[a][j][r] + bias[col];
                if constexpr (EP == EP_RELU) {
                    v = fmaxf(v, 0.f);
                } else {
                    v *= X[(long)(row - (sec << 12)) * 512 + col];
                }
                long o = (long)row * 512 + col;
                u16 h, l; splt(v, h, l);
                Ch[o] = h; Cl[o] = l;
            }
}

// ================= 128x128 dist GEMM: sT[b,q,key] = -(qs.ks/sqrt512)^2/2 =================
// grid MUST be (16,16,2) = 512 blocks (2/CU uniform). XCD owns one (batch, 8x8 quadrant).
__global__ __launch_bounds__(256)
void dist2(const u16* __restrict__ QH, const u16* __restrict__ QL,
           const u16* __restrict__ KH, const u16* __restrict__ KL,
           u16* __restrict__ S)
{
    __shared__ u16 LAh[2][128 * 32];
    __shared__ u16 LAl[2][128 * 32];
    __shared__ u16 LBh[2][128 * 32];
    __shared__ u16 LBl[2][128 * 32];

    const int tid = threadIdx.x;
    const int lane = tid & 63;
    const int wave = tid >> 6;
    const int wr = wave >> 1, wc = wave & 1;
    const int fr = lane & 15, kg = lane >> 4;

    const int L = (blockIdx.z * 16 + blockIdx.y) * 16 + blockIdx.x;
    const int xcd = L & 7;
    const int pos = L >> 3;                 // 0..63
    const int b = xcd >> 2, quad = xcd & 3;
    const int mi = (quad >> 1) * 8 + (pos >> 3);
    const int ni = (quad & 1) * 8 + (pos & 7);
    const int m0 = mi * 128, n0 = ni * 128;

    const u16* Ah = QH + (long)b * 1048576;
    const u16* Al = QL + (long)b * 1048576;
    const u16* Bh = KH + (long)b * 1048576;
    const u16* Bl = KL + (long)b * 1048576;

    f32x4 acc[4][4];
    #pragma unroll
    for (int a = 0; a < 4; ++a)
        #pragma unroll
        for (int j = 0; j < 4; ++j)
            acc[a][j] = (f32x4){0.f, 0.f, 0.f, 0.f};

    auto STAGE = [&](int buf, int kk) {
        #pragma unroll
        for (int h = 0; h < 2; ++h) {
            int c = h * 256 + tid;
            long so = (long)(m0 + (c >> 2)) * 512 + kk + (c & 3) * 8;
            gload16(Ah + so, &LAh[buf][c * 8]);
        }
        #pragma unroll
        for (int h = 0; h < 2; ++h) {
            int c = h * 256 + tid;
            long so = (long)(m0 + (c >> 2)) * 512 + kk + (c & 3) * 8;
            gload16(Al + so, &LAl[buf][c * 8]);
        }
        #pragma unroll
        for (int h = 0; h < 2; ++h) {
            int c = h * 256 + tid;
            long so = (long)(n0 + (c >> 2)) * 512 + kk + (c & 3) * 8;
            gload16(Bh + so, &LBh[buf][c * 8]);
        }
        #pragma unroll
        for (int h = 0; h < 2; ++h) {
            int c = h * 256 + tid;
            long so = (long)(n0 + (c >> 2)) * 512 + kk + (c & 3) * 8;
            gload16(Bl + so, &LBl[buf][c * 8]);
        }
    };

    auto COMPUTE = [&](int buf) {
        short8 ah[4], al[4], bh[4], bl[4];
        #pragma unroll
        for (int a = 0; a < 4; ++a) {
            int off = (wr * 64 + a * 16 + fr) * 32 + kg * 8;
            ah[a] = *(const short8*)&LAh[buf][off];
            al[a] = *(const short8*)&LAl[buf][off];
        }
        #pragma unroll
        for (int j = 0; j < 4; ++j) {
            int off = (wc * 64 + j * 16 + fr) * 32 + kg * 8;
            bh[j] = *(const short8*)&LBh[buf][off];
            bl[j] = *(const short8*)&LBl[buf][off];
        }
        #pragma unroll
        for (int a = 0; a < 4; ++a)
            #pragma unroll
            for (int j = 0; j < 4; ++j) {
                acc[a][j] = __builtin_amdgcn_mfma_f32_16x16x32_bf16(ah[a], bh[j], acc[a][j], 0, 0, 0);
                acc[a][j] = __builtin_amdgcn_mfma_f32_16x16x32_bf16(ah[a], bl[j], acc[a][j], 0, 0, 0);
                acc[a][j] = __builtin_amdgcn_mfma_f32_16x16x32_bf16(al[a], bh[j], acc[a][j], 0, 0, 0);
            }
    };

    STAGE(0, 0);
    int cur = 0;
    for (int t = 0; t < 15; ++t) {
        STAGE(cur ^ 1, (t + 1) << 5);
        asm volatile("s_waitcnt vmcnt(8)" ::: "memory");
        __builtin_amdgcn_s_barrier();
        COMPUTE(cur);
        __builtin_amdgcn_s_barrier();
        cur ^= 1;
    }
    asm volatile("s_waitcnt vmcnt(0)" ::: "memory");
    __builtin_amdgcn_s_barrier();
    COMPUTE(cur);

    u16* Sb = S + (long)b * 8388608;
    #pragma unroll
    for (int a = 0; a < 4; ++a)
        #pragma unroll
        for (int j = 0; j < 4; ++j)
            #pragma unroll
            for (int r = 0; r < 4; ++r) {
                int row = m0 + wr * 64 + a * 16 + kg * 4 + r;
                int col = n0 + wc * 64 + j * 16 + fr;
                float v = acc[a][j][r];
                v = -(v * v) * (1.0f / 1024.0f);
                u16 h, l; splt(v, h, l);
                u16* p = Sb + (long)row * 4096 + col;
                p[0] = h; p[2048] = l;
            }
}

// ================= 128x128 split-K GEMM (context) =================
// grid (4,16,8): gz = b*4 + s; contiguous-panel XCD remap; partials f32.
// s<3 -> Cf0[(b*3+s)<<20]; s==3 -> Cf3[b<<20].
__global__ __launch_bounds__(256)
void gemm2(const u16* __restrict__ Ah, const u16* __restrict__ Al, int lda, long sA,
           const u16* __restrict__ Bh, const u16* __restrict__ Bl, int ldb, long sB,
           float* __restrict__ Cf0, float* __restrict__ Cf3)
{
    __shared__ u16 LAh[2][128 * 32];
    __shared__ u16 LAl[2][128 * 32];
    __shared__ u16 LBh[2][128 * 32];
    __shared__ u16 LBl[2][128 * 32];

    const int tid = threadIdx.x;
    const int lane = tid & 63;
    const int wave = tid >> 6;
    const int wr = wave >> 1, wc = wave & 1;
    const int fr = lane & 15, kg = lane >> 4;

    // contiguous panel pinning: P = 16*8 = 128 panels, 16 per XCD
    const int L = (blockIdx.z * 16 + blockIdx.y) * 4 + blockIdx.x;
    const int xcd = L & 7;
    const int i = L >> 3;                 // 0..63
    const int bx = i & 3;
    const int panel = xcd * 16 + (i >> 2);
    const int by = panel & 15;
    const int bz = panel >> 4;            // 0..7
    const int b = bz >> 2, s = bz & 3;
    const int k0 = s << 9;                // KS = 512

    Ah += b * sA; Al += b * sA;
    Bh += b * sB; Bl += b * sB;
    float* Cf = (s < 3) ? (Cf0 + ((long)(b * 3 + s) << 20))
                        : (Cf3 + ((long)b << 20));

    const int m0 = by * 128, n0 = bx * 128;

    f32x4 acc[4][4];
    #pragma unroll
    for (int a = 0; a < 4; ++a)
        #pragma unroll
        for (int j = 0; j < 4; ++j)
            acc[a][j] = (f32x4){0.f, 0.f, 0.f, 0.f};

    auto STAGE = [&](int buf, int kk) {
        #pragma unroll
        for (int h = 0; h < 2; ++h) {
            int c = h * 256 + tid;
            long so = (long)(m0 + (c >> 2)) * lda + kk + (c & 3) * 8;
            gload16(Ah + so, &LAh[buf][c * 8]);
        }
        #pragma unroll
        for (int h = 0; h < 2; ++h) {
            int c = h * 256 + tid;
            long so = (long)(m0 + (c >> 2)) * lda + kk + (c & 3) * 8;
            gload16(Al + so, &LAl[buf][c * 8]);
        }
        #pragma unroll
        for (int h = 0; h < 2; ++h) {
            int c = h * 256 + tid;
            long so = (long)(n0 + (c >> 2)) * ldb + kk + (c & 3) * 8;
            gload16(Bh + so, &LBh[buf][c * 8]);
        }
        #pragma unroll
        for (int h = 0; h < 2; ++h) {
            int c = h * 256 + tid;
            long so = (long)(n0 + (c >> 2)) * ldb + kk + (c & 3) * 8;
            gload16(Bl + so, &LBl[buf][c * 8]);
        }
    };

    auto COMPUTE = [&](int buf) {
        short8 ah[4], al[4], bh[4], bl[4];
        #pragma unroll
        for (int a = 0; a < 4; ++a) {
            int off = (wr * 64 + a * 16 + fr) * 32 + kg * 8;
            ah[a] = *(const short8*)&LAh[buf][off];
            al[a] = *(const short8*)&LAl[buf][off];
        }
        #pragma unroll
        for (int j = 0; j < 4; ++j) {
            int off = (wc * 64 + j * 16 + fr) * 32 + kg * 8;
            bh[j] = *(const short8*)&LBh[buf][off];
            bl[j] = *(const short8*)&LBl[buf][off];
        }
        #pragma unroll
        for (int a = 0; a < 4; ++a)
            #pragma unroll
            for (int j = 0; j < 4; ++j) {
                acc[a][j] = __builtin_amdgcn_mfma_f32_16x16x32_bf16(ah[a], bh[j], acc[a][j], 0, 0, 0);
                acc[a][j] = __builtin_amdgcn_mfma_f32_16x16x32_bf16(ah[a], bl[j], acc[a][j], 0, 0, 0);
                acc[a][j] = __builtin_amdgcn_mfma_f32_16x16x32_bf16(al[a], bh[j], acc[a][j], 0, 0, 0);
            }
    };

    STAGE(0, k0);
    int cur = 0;
    for (int t = 0; t < 15; ++t) {
        STAGE(cur ^ 1, k0 + ((t + 1) << 5));
        asm volatile("s_waitcnt vmcnt(8)" ::: "memory");
        __builtin_amdgcn_s_barrier();
        COMPUTE(cur);
        __builtin_amdgcn_s_barrier();
        cur ^= 1;
    }
    asm volatile("s_waitcnt vmcnt(0)" ::: "memory");
    __builtin_amdgcn_s_barrier();
    COMPUTE(cur);

    #pragma unroll
    for (int a = 0; a < 4; ++a)
        #pragma unroll
        for (int j = 0; j < 4; ++j)
            #pragma unroll
            for (int r = 0; r < 4; ++r) {
                int row = m0 + wr * 64 + a * 16 + kg * 4 + r;
                int col = n0 + wc * 64 + j * 16 + fr;
                Cf[(long)row * 512 + col] = acc[a][j][r];
            }
}

// ================= generic 128x64 split GEMM with XCD remap (outproj) =================
template<int EP>
__global__ __launch_bounds__(256)
void gemm_pf(int K, int nsl, int KS,
             const u16* __restrict__ Ah, const u16* __restrict__ Al, int lda, long sA,
             const u16* __restrict__ Bh, const u16* __restrict__ Bl, int ldb, long sB,
             float* __restrict__ Cf, int ldc, long sC)
{
    __shared__ u16 LAh[2][128 * 32];
    __shared__ u16 LAl[2][128 * 32];
    __shared__ u16 LBh[2][64 * 32];
    __shared__ u16 LBl[2][64 * 32];

    const int tid = threadIdx.x;
    const int lane = tid & 63;
    const int wave = tid >> 6;
    const int wr = wave >> 1, wc = wave & 1;
    const int fr = lane & 15, kg = lane >> 4;

    int bx, by, bz;
    {
        const int gx = gridDim.x, gy = gridDim.y;
        const int L = (blockIdx.z * gy + blockIdx.y) * gx + blockIdx.x;
        const int xcd = L & 7;
        const int i = L >> 3;
        const int P = gy * gridDim.z;
        const int ppx = P >> 3;
        bx = i % gx;
        const int panel = xcd * ppx + i / gx;
        by = panel % gy;
        bz = panel / gy;
    }

    const int b = bz / nsl;
    const int s = bz - b * nsl;
    const int k0 = s * KS;
    int k1 = k0 + KS; if (k1 > K) k1 = K;
    const int nt = (k1 - k0) >> 5;

    Ah += b * sA; Al += b * sA;
    Bh += b * sB; Bl += b * sB;
    const long cb = (long)bz * sC;

    const int m0 = by * 128, n0 = bx * 64;

    f32x4 acc[4][2];
    #pragma unroll
    for (int a = 0; a < 4; ++a)
        #pragma unroll
        for (int j = 0; j < 2; ++j)
            acc[a][j] = (f32x4){0.f, 0.f, 0.f, 0.f};

    auto STAGE = [&](int buf, int kk) {
        #pragma unroll
        for (int h = 0; h < 2; ++h) {
            int c = h * 256 + tid;
            long so = (long)(m0 + (c >> 2)) * lda + kk + (c & 3) * 8;
            gload16(Ah + so, &LAh[buf][c * 8]);
        }
        #pragma unroll
        for (int h = 0; h < 2; ++h) {
            int c = h * 256 + tid;
            long so = (long)(m0 + (c >> 2)) * lda + kk + (c & 3) * 8;
            gload16(Al + so, &LAl[buf][c * 8]);
        }
        {
            int c = tid;
            long so = (long)(n0 + (c >> 2)) * ldb + kk + (c & 3) * 8;
            gload16(Bh + so, &LBh[buf][c * 8]);
            gload16(Bl + so, &LBl[buf][c * 8]);
        }
    };

    auto COMPUTE = [&](int buf) {
        short8 ah[4], al[4], bh[2], bl[2];
        #pragma unroll
        for (int a = 0; a < 4; ++a) {
            int off = (wr * 64 + a * 16 + fr) * 32 + kg * 8;
            ah[a] = *(const short8*)&LAh[buf][off];
            al[a] = *(const short8*)&LAl[buf][off];
        }
        #pragma unroll
        for (int j = 0; j < 2; ++j) {
            int off = (wc * 32 + j * 16 + fr) * 32 + kg * 8;
            bh[j] = *(const short8*)&LBh[buf][off];
            bl[j] = *(const short8*)&LBl[buf][off];
        }
        #pragma unroll
        for (int a = 0; a < 4; ++a)
            #pragma unroll
            for (int j = 0; j < 2; ++j) {
                acc[a][j] = __builtin_amdgcn_mfma_f32_16x16x32_bf16(ah[a], bh[j], acc[a][j], 0, 0, 0);
                acc[a][j] = __builtin_amdgcn_mfma_f32_16x16x32_bf16(ah[a], bl[j], acc[a][j], 0, 0, 0);
                acc[a][j] = __builtin_amdgcn_mfma_f32_16x16x32_bf16(al[a], bh[j], acc[a][j], 0, 0, 0);
            }
    };

    STAGE(0, k0);
    int cur = 0;
    for (int t = 0; t < nt - 1; ++t) {
        STAGE(cur ^ 1, k0 + ((t + 1) << 5));
        asm volatile("s_waitcnt vmcnt(6)" ::: "memory");
        __builtin_amdgcn_s_barrier();
        COMPUTE(cur);
        __builtin_amdgcn_s_barrier();
        cur ^= 1;
    }
    asm volatile("s_waitcnt vmcnt(0)" ::: "memory");
    __builtin_amdgcn_s_barrier();
    COMPUTE(cur);

    #pragma unroll
    for (int a = 0; a < 4; ++a)
        #pragma unroll
        for (int j = 0; j < 2; ++j)
            #pragma unroll
            for (int r = 0; r < 4; ++r) {
                int row = m0 + wr * 64 + a * 16 + kg * 4 + r;
                int col = n0 + wc * 32 + j * 16 + fr;
                Cf[cb + (long)row * ldc + col] = acc[a][j][r];
            }
}

// softmax over 2048 keys; in/out = hi/lo bf16 pairs, row stride 4096 u16
__global__ __launch_bounds__(256)
void softmax16(u16* __restrict__ S)
{
    long row = blockIdx.x;
    u16* hi = S + row * 4096;
    u16* lo = hi + 2048;
    int tid = threadIdx.x;
    int lane = tid & 63, w = tid >> 6;

    u16x4 h0 = ((u16x4*)hi)[tid * 2];
    u16x4 h1 = ((u16x4*)hi)[tid * 2 + 1];
    u16x4 l0 = ((u16x4*)lo)[tid * 2];
    u16x4 l1 = ((u16x4*)lo)[tid * 2 + 1];

    float v[8];
    #pragma unroll
    for (int i = 0; i < 4; ++i) {
        v[i]     = bf2f(h0[i]) + bf2f(l0[i]);
        v[4 + i] = bf2f(h1[i]) + bf2f(l1[i]);
    }

    float m = v[0];
    #pragma unroll
    for (int i = 1; i < 8; ++i) m = fmaxf(m, v[i]);
    #pragma unroll
    for (int o = 32; o; o >>= 1) m = fmaxf(m, __shfl_xor(m, o));

    __shared__ float redm[4];
    __shared__ float reds[4];
    if (lane == 0) redm[w] = m;
    __syncthreads();
    m = fmaxf(fmaxf(redm[0], redm[1]), fmaxf(redm[2], redm[3]));

    float s = 0.f;
    #pragma unroll
    for (int i = 0; i < 8; ++i) { v[i] = expf(v[i] - m); s += v[i]; }
    #pragma unroll
    for (int o = 32; o; o >>= 1) s += __shfl_xor(s, o);
    if (lane == 0) reds[w] = s;
    __syncthreads();
    s = reds[0] + reds[1] + reds[2] + reds[3];
    float inv = 1.0f / s;

    u16 h, l;
    #pragma unroll
    for (int i = 0; i < 4; ++i) {
        splt(v[i] * inv, h, l);     h0[i] = h; l0[i] = l;
        splt(v[4 + i] * inv, h, l); h1[i] = h; l1[i] = l;
    }
    ((u16x4*)hi)[tid * 2] = h0;
    ((u16x4*)hi)[tid * 2 + 1] = h1;
    ((u16x4*)lo)[tid * 2] = l0;
    ((u16x4*)lo)[tid * 2 + 1] = l1;
}

// vs hi/lo [4096,512] (2 batches of 2048) -> vsT hi/lo [2][512][2048]
__global__ __launch_bounds__(256)
void transpose16(const u16* __restrict__ vH, const u16* __restrict__ vL,
                 u16* __restrict__ tH, u16* __restrict__ tL)
{
    __shared__ float t[32][33];
    int b = blockIdx.z;
    int c0 = blockIdx.x * 32;
    int r0 = blockIdx.y * 32;
    int tx = threadIdx.x, ty = threadIdx.y;
    #pragma unroll
    for (int k = 0; k < 4; ++k) {
        long idx = (long)(b * 2048 + r0 + ty + 8 * k) * 512 + c0 + tx;
        t[ty + 8 * k][tx] = bf2f(vH[idx]) + bf2f(vL[idx]);
    }
    __syncthreads();
    long ob = (long)b * 512 * 2048;
    #pragma unroll
    for (int k = 0; k < 4; ++k) {
        float v = t[tx][ty + 8 * k];
        u16 h, l; splt(v, h, l);
        long o = ob + (long)(c0 + ty + 8 * k) * 2048 + r0 + tx;
        tH[o] = h; tL[o] = l;
    }
}

// fused input+weight split, one launch. grid (2048, 4).
// y<3: input section y (KEY/QUERY/VALUE) -> stacked [12288,512] hi/lo.
// y==3: all 7 weights; gid = x*256+tid; w = gid>>16 (65536 float4 per weight).
__global__ __launch_bounds__(256)
void split_all(const float* __restrict__ k, const float* __restrict__ q,
               const float* __restrict__ vv,
               const float* __restrict__ w0, const float* __restrict__ w1,
               const float* __restrict__ w2, const float* __restrict__ w3,
               const float* __restrict__ w4, const float* __restrict__ w5,
               const float* __restrict__ w6,
               u16* __restrict__ inHi, u16* __restrict__ inLo,
               u16* __restrict__ wdst)
{
    int sec = blockIdx.y;
    if (sec < 3) {
        const float* src = (sec == 0) ? k : (sec == 1) ? q : vv;
        long base4 = (long)sec * 524288;
        int i = blockIdx.x * 256 + threadIdx.x;
        float4 v = ((const float4*)src)[i];
        u16x4 h4, l4; u16 h, l;
        splt(v.x, h, l); h4.x = h; l4.x = l;
        splt(v.y, h, l); h4.y = h; l4.y = l;
        splt(v.z, h, l); h4.z = h; l4.z = l;
        splt(v.w, h, l); h4.w = h; l4.w = l;
        ((u16x4*)inHi)[base4 + i] = h4;
        ((u16x4*)inLo)[base4 + i] = l4;
    } else {
        int gid = blockIdx.x * 256 + threadIdx.x;   // 0..524287
        int w = gid >> 16;                          // 65536 float4 per weight
        if (w >= 7) return;
        int i = gid & 65535;
        const float* src;
        switch (w) {
            case 0: src = w0; break; case 1: src = w1; break;
            case 2: src = w2; break; case 3: src = w3; break;
            case 4: src = w4; break; case 5: src = w5; break;
            default: src = w6; break;
        }
        u16* hi = wdst + (long)w * 524288;
        u16* lo = hi + 262144;
        float4 v = ((const float4*)src)[i];
        u16x4 h4, l4; u16 h, l;
        splt(v.x, h, l); h4.x = h; l4.x = l;
        splt(v.y, h, l); h4.y = h; l4.y = l;
        splt(v.z, h, l); h4.z = h; l4.z = l;
        splt(v.w, h, l); h4.w = h; l4.w = l;
        ((u16x4*)hi)[i] = h4;
        ((u16x4*)lo)[i] = l4;
    }
}

// ct = split(sum of 4 ctx partials); P012 layout [b*3+s][2^20], P3 layout [b][2^20]
__global__ __launch_bounds__(256)
void reduce_ctx4(const float* __restrict__ P012, const float* __restrict__ P3,
                 u16* __restrict__ ctH, u16* __restrict__ ctL)
{
    int i4 = blockIdx.x * 256 + threadIdx.x;     // 524288 float4s
    long e = (long)i4 * 4;
    int b = (int)(e >> 20);
    long r = e & ((1L << 20) - 1);
    const float* base = P012 + ((long)(b * 3) << 20) + r;
    float4 v0 = *(const float4*)base;
    float4 v1 = *(const float4*)(base + (1L << 20));
    float4 v2 = *(const float4*)(base + (2L << 20));
    float4 v3 = *(const float4*)(P3 + ((long)b << 20) + r);
    u16x4 h4, l4; u16 h, l;
    splt(v0.x + v1.x + v2.x + v3.x, h, l); h4.x = h; l4.x = l;
    splt(v0.y + v1.y + v2.y + v3.y, h, l); h4.y = h; l4.y = l;
    splt(v0.z + v1.z + v2.z + v3.z, h, l); h4.z = h; l4.z = l;
    splt(v0.w + v1.w + v2.w + v3.w, h, l); h4.w = h; l4.w = l;
    ((u16x4*)ctH)[i4] = h4;
    ((u16x4*)ctL)[i4] = l4;
}

// out = P0 + P1 + bias
__global__ __launch_bounds__(256)
void reduce_out(const float* __restrict__ P, const float* __restrict__ bias,
                float* __restrict__ out)
{
    int i4 = blockIdx.x * 256 + threadIdx.x;     // 524288 float4s
    long e = (long)i4 * 4;
    float4 a = ((const float4*)P)[i4];
    float4 c = ((const float4*)(P + 2097152))[i4];
    float4 bb = *(const float4*)(bias + (e & 511));
    float4 o;
    o.x = a.x + c.x + bb.x;
    o.y = a.y + c.y + bb.y;
    o.z = a.z + c.z + bb.z;
    o.w = a.w + c.w + bb.w;
    ((float4*)out)[i4] = o;
}

extern "C" void kernel_launch(void* const* d_in, const int* in_sizes, int n_in,
                              void* d_out, int out_size, void* d_ws, size_t ws_size,
                              hipStream_t stream)
{
    const float* KEY   = (const float*)d_in[0];
    const float* VALUE = (const float*)d_in[1];
    const float* QUERY = (const float*)d_in[2];
    const float* W1w = (const float*)d_in[3];
    const float* W1b = (const float*)d_in[4];
    const float* W2w = (const float*)d_in[5];
    const float* W2b = (const float*)d_in[6];
    const float* W3w = (const float*)d_in[7];
    const float* W3b = (const float*)d_in[8];
    const float* V1w = (const float*)d_in[9];
    const float* V1b = (const float*)d_in[10];
    const float* V2w = (const float*)d_in[11];
    const float* V2b = (const float*)d_in[12];
    const float* V3w = (const float*)d_in[13];
    const float* V3b = (const float*)d_in[14];
    const float* Wow = (const float*)d_in[15];
    const float* Wob = (const float*)d_in[16];
    float* out = (float*)d_out;

    const long SEC  = 4096L * 512;     // 2,097,152 u16 per section
    const long FULL = 3 * SEC;         // 6,291,456

    // ---- workspace layout (82,837,504 B total, identical to proven R10) ----
    u16* Wb = (u16*)d_ws;                        // 7 x (hi|lo) = 3,670,016 u16
    u16* cH = Wb + 3670016;                      // [12288,512] hi
    u16* cL = cH + FULL;                         // lo
    u16* R1 = cL + FULL;                         // 4*FULL u16 region
    u16* h1H = R1,            *h1L = R1 + FULL;
    u16* h2H = R1 + 2 * FULL, *h2L = R1 + 3 * FULL;
    // post-L3 aliases inside R1 (h1,h2 dead):
    u16* sTu = R1;                               // scores [2][2048][4096] u16 (33.5 MB)
    u16* vtH = R1 + 16777216;                    // vsT hi [2][512][2048]
    u16* vtL = vtH + 2097152;
    // ctx partials: slices s<3 in c region (24 MB), s==3 in R1 tail (8 MB)
    float* Pctx012 = (float*)cH;                 // [2*3][2^20] f32
    float* Pctx3   = (float*)(R1 + 20971520);    // [2][2^20] f32
    // after ctx: sTu dead -> ct + Pout live there
    u16* ctH = R1;                               // ctx hi [4096,512]
    u16* ctL = R1 + 2097152;
    float* Pout = (float*)(R1 + 4194304);        // [2][2^21] f32 = 16 MB

    u16* wH6 = Wb + 6L * 524288;
    u16* wL6 = wH6 + 262144;

    dim3 blk(256);

    split_all<<<dim3(2048, 4), blk, 0, stream>>>(
        KEY, QUERY, VALUE, W1w, W2w, W3w, V1w, V2w, V3w, Wow, cH, cL, Wb);

    // ---- merged MLP: 3 layers over 12288 rows (c -> h1 -> h2 -> c) ----
    dim3 gL(8, 96, 1);
    mlp_pf<EP_RELU><<<gL, blk, 0, stream>>>(
        cH, cL, Wb, Wb + 262144, Wb + 3 * 524288, Wb + 3 * 524288 + 262144,
        W1b, V1b, nullptr, nullptr, nullptr, h1H, h1L);
    mlp_pf<EP_RELU><<<gL, blk, 0, stream>>>(
        h1H, h1L, Wb + 524288, Wb + 524288 + 262144, Wb + 4 * 524288, Wb + 4 * 524288 + 262144,
        W2b, V2b, nullptr, nullptr, nullptr, h2H, h2L);
    mlp_pf<EP_MUL><<<gL, blk, 0, stream>>>(
        h2H, h2L, Wb + 2 * 524288, Wb + 2 * 524288 + 262144, Wb + 5 * 524288, Wb + 5 * 524288 + 262144,
        W3b, V3b, KEY, QUERY, VALUE, cH, cL);
    // c now holds: ks rows 0-4095, qs rows 4096-8191, vs rows 8192-12287

    // vs -> vsT hi/lo
    transpose16<<<dim3(16, 64, 2), dim3(32, 8), 0, stream>>>(
        cH + 2 * SEC, cL + 2 * SEC, vtH, vtL);

    // dist: sT[b,q,key] hi/lo — 128x128 tiles, 512 blocks = 2/CU uniform
    dist2<<<dim3(16, 16, 2), blk, 0, stream>>>(
        cH + SEC, cL + SEC,      // qs hi/lo
        cH, cL,                  // ks hi/lo
        sTu);

    // softmax over keys (hi/lo in place)
    softmax16<<<dim3(4096), blk, 0, stream>>>(sTu);

    // context: 128x128 tiles, split-K4, 512 blocks = 2/CU uniform
    gemm2<<<dim3(4, 16, 8), blk, 0, stream>>>(
        sTu, sTu + 2048, 4096, 8388608,
        vtH, vtL, 2048, 1048576,
        Pctx012, Pctx3);

    reduce_ctx4<<<dim3(2048), blk, 0, stream>>>(Pctx012, Pctx3, ctH, ctL);

    // output projection split-K2 (512 blocks = 2/CU)
    gemm_pf<EP_PART><<<dim3(8, 32, 2), blk, 0, stream>>>(
        512, 2, 256,
        ctH, ctL, 512, 0,
        wH6, wL6, 512, 0,
        Pout, 512, 2097152);

    reduce_out<<<dim3(2048), blk, 0, stream>>>(Pout, Wob, out);
}